// Round 1
// baseline (1450.417 us; speedup 1.0000x reference)
//
#include <hip/hip_runtime.h>

#define NUM_USER 200000
#define NUM_EVENT 50000
#define NUM_EDGES 1000000
#define DDIM 64

// y[r][j] = sum_k x[r][k] * W[j][k] + b[j]; dual-store into y and acc.
// W column j held in registers of lane j's thread; x row broadcast via shfl.
// NOTE: x and acc may alias (layer-2 in-place): no __restrict__ on them; the
// row is fully read into a register before the store, and each row is touched
// by exactly one wave iteration.
__global__ __launch_bounds__(256) void linear_dual_kernel(
    const float* x, const float* __restrict__ W, const float* __restrict__ b,
    float* __restrict__ y, float* acc, int n) {
  const int lane = threadIdx.x & 63;
  const int wave = blockIdx.x * (blockDim.x >> 6) + (threadIdx.x >> 6);
  const int nwaves = gridDim.x * (blockDim.x >> 6);

  // Load W column `lane`: w[k] = W[lane*64 + k]
  float w[DDIM];
#pragma unroll
  for (int k4 = 0; k4 < DDIM / 4; ++k4) {
    float4 t = reinterpret_cast<const float4*>(W)[lane * (DDIM / 4) + k4];
    w[k4 * 4 + 0] = t.x;
    w[k4 * 4 + 1] = t.y;
    w[k4 * 4 + 2] = t.z;
    w[k4 * 4 + 3] = t.w;
  }
  const float bj = b[lane];

  for (int r = wave; r < n; r += nwaves) {
    const float xv = x[r * DDIM + lane];  // read full row before any store
    float accv = bj;
#pragma unroll
    for (int k = 0; k < DDIM; ++k) {
      accv += __shfl(xv, k) * w[k];
    }
    y[r * DDIM + lane] = accv;
    acc[r * DDIM + lane] = accv;
  }
}

__global__ __launch_bounds__(256) void degree_kernel(
    const int* __restrict__ src, const int* __restrict__ dst,
    float* __restrict__ deg_e, float* __restrict__ deg_u, int E) {
  int i = blockIdx.x * blockDim.x + threadIdx.x;
  if (i < E) {
    unsafeAtomicAdd(&deg_e[src[i]], 1.0f);
    unsafeAtomicAdd(&deg_u[dst[i]], 1.0f);
  }
}

// For each edge: acc_u[dst] += xe[src]; acc_e[src] += xu[dst]. One wave per
// edge iteration; lane = feature dim.
__global__ __launch_bounds__(256) void scatter_edges_kernel(
    const int* __restrict__ src, const int* __restrict__ dst,
    const float* __restrict__ xe, const float* __restrict__ xu,
    float* __restrict__ acc_u, float* __restrict__ acc_e, int E) {
  const int lane = threadIdx.x & 63;
  const int wave = blockIdx.x * (blockDim.x >> 6) + (threadIdx.x >> 6);
  const int nwaves = gridDim.x * (blockDim.x >> 6);
  for (int e = wave; e < E; e += nwaves) {
    const int s = src[e];
    const int d = dst[e];
    const float ve = xe[s * DDIM + lane];
    const float vu = xu[d * DDIM + lane];
    unsafeAtomicAdd(&acc_u[d * DDIM + lane], ve);
    unsafeAtomicAdd(&acc_e[s * DDIM + lane], vu);
  }
}

// acc[row][:] *= 1/(deg[row]+1), in place, float4 per thread.
__global__ __launch_bounds__(256) void finalize_kernel(
    float* __restrict__ acc, const float* __restrict__ deg, int n) {
  int i = blockIdx.x * blockDim.x + threadIdx.x;
  if (i < n * (DDIM / 4)) {
    const int row = i / (DDIM / 4);
    const float r = 1.0f / (deg[row] + 1.0f);
    float4 v = reinterpret_cast<float4*>(acc)[i];
    v.x *= r;
    v.y *= r;
    v.z *= r;
    v.w *= r;
    reinterpret_cast<float4*>(acc)[i] = v;
  }
}

extern "C" void kernel_launch(void* const* d_in, const int* in_sizes, int n_in,
                              void* d_out, int out_size, void* d_ws,
                              size_t ws_size, hipStream_t stream) {
  const float* x_user = (const float*)d_in[0];
  const float* x_event = (const float*)d_in[1];
  const int* src = (const int*)d_in[2];
  const int* dst = (const int*)d_in[3];
  const float* Wu0 = (const float*)d_in[4];
  const float* bu0 = (const float*)d_in[5];
  const float* We0 = (const float*)d_in[6];
  const float* be0 = (const float*)d_in[7];
  const float* Wu1 = (const float*)d_in[8];
  const float* bu1 = (const float*)d_in[9];
  const float* We1 = (const float*)d_in[10];
  const float* be1 = (const float*)d_in[11];

  float* ws = (float*)d_ws;
  float* xu_lin = ws;                              // 12,800,000 floats
  float* xe_lin = ws + (size_t)NUM_USER * DDIM;    // 3,200,000 floats
  float* deg_u = xe_lin + (size_t)NUM_EVENT * DDIM;  // 200,000
  float* deg_e = deg_u + NUM_USER;                   // 50,000

  float* acc_u = (float*)d_out;                    // user segment of output
  float* acc_e = acc_u + (size_t)NUM_USER * DDIM;  // event segment

  // Degrees (shared by both layers)
  hipMemsetAsync(deg_u, 0, (NUM_USER + NUM_EVENT) * sizeof(float), stream);
  degree_kernel<<<(NUM_EDGES + 255) / 256, 256, 0, stream>>>(src, dst, deg_e,
                                                             deg_u, NUM_EDGES);

  const int lin_grid = 2048;
  const int sc_grid = 16384;
  const int fin_grid_u = (NUM_USER * (DDIM / 4) + 255) / 256;
  const int fin_grid_e = (NUM_EVENT * (DDIM / 4) + 255) / 256;

  // ---- Layer 1 ----
  linear_dual_kernel<<<lin_grid, 256, 0, stream>>>(x_user, Wu0, bu0, xu_lin,
                                                   acc_u, NUM_USER);
  linear_dual_kernel<<<lin_grid, 256, 0, stream>>>(x_event, We0, be0, xe_lin,
                                                   acc_e, NUM_EVENT);
  scatter_edges_kernel<<<sc_grid, 256, 0, stream>>>(src, dst, xe_lin, xu_lin,
                                                    acc_u, acc_e, NUM_EDGES);
  finalize_kernel<<<fin_grid_u, 256, 0, stream>>>(acc_u, deg_u, NUM_USER);
  finalize_kernel<<<fin_grid_e, 256, 0, stream>>>(acc_e, deg_e, NUM_EVENT);

  // ---- Layer 2 (inputs are layer-1 outputs living in d_out; in-place) ----
  linear_dual_kernel<<<lin_grid, 256, 0, stream>>>(acc_u, Wu1, bu1, xu_lin,
                                                   acc_u, NUM_USER);
  linear_dual_kernel<<<lin_grid, 256, 0, stream>>>(acc_e, We1, be1, xe_lin,
                                                   acc_e, NUM_EVENT);
  scatter_edges_kernel<<<sc_grid, 256, 0, stream>>>(src, dst, xe_lin, xu_lin,
                                                    acc_u, acc_e, NUM_EDGES);
  finalize_kernel<<<fin_grid_u, 256, 0, stream>>>(acc_u, deg_u, NUM_USER);
  finalize_kernel<<<fin_grid_e, 256, 0, stream>>>(acc_e, deg_e, NUM_EVENT);
}

// Round 2
// 864.812 us; speedup vs baseline: 1.6771x; 1.6771x over previous
//
#include <hip/hip_runtime.h>

#define NUM_USER 200000
#define NUM_EVENT 50000
#define NUM_EDGES 1000000
#define DDIM 64
#define LDP 68  // LDS leading dim: 64+4 keeps 16B alignment; stride-68 banks are 2-way max (free)

// ---------------- CSR build ----------------

// counts[dst[i]]++ ; counts[NUM_USER + src[i]]++
__global__ __launch_bounds__(256) void histogram_kernel(
    const int* __restrict__ src, const int* __restrict__ dst,
    int* __restrict__ cnt, int E) {
  int i = blockIdx.x * blockDim.x + threadIdx.x;
  if (i < E) {
    atomicAdd(&cnt[dst[i]], 1);
    atomicAdd(&cnt[NUM_USER + src[i]], 1);
  }
}

// Exclusive scan, 2048 elements per block (256 threads x 8). Writes per-block
// total to bsums[bid]; data[] becomes block-local exclusive scan.
__global__ __launch_bounds__(256) void scan_local_kernel(
    int* __restrict__ data, int* __restrict__ bsums, int N) {
  __shared__ int sdata[256];
  const int tid = threadIdx.x;
  const int base = blockIdx.x * 2048 + tid * 8;
  int v[8];
  int s = 0;
#pragma unroll
  for (int j = 0; j < 8; ++j) {
    v[j] = (base + j < N) ? data[base + j] : 0;
    s += v[j];
  }
  sdata[tid] = s;
  __syncthreads();
  for (int off = 1; off < 256; off <<= 1) {
    int t = (tid >= off) ? sdata[tid - off] : 0;
    __syncthreads();
    sdata[tid] += t;
    __syncthreads();
  }
  if (tid == 255) bsums[blockIdx.x] = sdata[255];
  int run = (tid == 0) ? 0 : sdata[tid - 1];
#pragma unroll
  for (int j = 0; j < 8; ++j) {
    int t = v[j];
    if (base + j < N) data[base + j] = run;
    run += t;
  }
}

// Exclusive scan of the <=256 block sums, in place. One block.
__global__ __launch_bounds__(256) void scan_bsums_kernel(int* __restrict__ bsums, int nb) {
  __shared__ int sdata[256];
  const int tid = threadIdx.x;
  int s = (tid < nb) ? bsums[tid] : 0;
  sdata[tid] = s;
  __syncthreads();
  for (int off = 1; off < 256; off <<= 1) {
    int t = (tid >= off) ? sdata[tid - off] : 0;
    __syncthreads();
    sdata[tid] += t;
    __syncthreads();
  }
  if (tid < nb) bsums[tid] = sdata[tid] - s;  // exclusive
}

__global__ __launch_bounds__(256) void scan_add_kernel(
    int* __restrict__ data, const int* __restrict__ bsums, int N) {
  const int base = blockIdx.x * 2048 + threadIdx.x * 8;
  const int add = bsums[blockIdx.x];
#pragma unroll
  for (int j = 0; j < 8; ++j) {
    if (base + j < N) data[base + j] += add;
  }
}

// Fill lists via atomic cursors ON offs itself. Afterwards offs[g] holds the
// END of segment g (i.e. original offs[g+1]); readers use start = offs[g-1].
__global__ __launch_bounds__(256) void fill_kernel(
    const int* __restrict__ src, const int* __restrict__ dst,
    int* __restrict__ offs, int* __restrict__ lists, int E) {
  int i = blockIdx.x * blockDim.x + threadIdx.x;
  if (i < E) {
    const int s = src[i];
    const int d = dst[i];
    int pu = atomicAdd(&offs[d], 1);
    lists[pu] = s;
    int pe = atomicAdd(&offs[NUM_USER + s], 1);
    lists[pe] = d;
  }
}

// ---------------- Linear: y = x @ W^T + b (LDS-tiled, 4x4 register block) ----------------

__global__ __launch_bounds__(256) void linear_tiled_kernel(
    const float* __restrict__ x, const float* __restrict__ W,
    const float* __restrict__ b, float* __restrict__ y, int n, int ntiles) {
  __shared__ float xT[64 * LDP];  // xT[k][r]
  __shared__ float wT[64 * LDP];  // wT[k][c] = W[c][k]
  const int tid = threadIdx.x;
  const int r64 = tid & 63;  // staging: row/col index (lane-fast -> conflict-free LDS writes)
  const int q = tid >> 6;    // staging: chunk group

  // Stage W^T once per block.
  {
    const int c = r64;
    const float4* wr = reinterpret_cast<const float4*>(W + (size_t)c * DDIM);
#pragma unroll
    for (int i = 0; i < 4; ++i) {
      const int kc4 = q * 4 + i;
      float4 t = wr[kc4];
      wT[(kc4 * 4 + 0) * LDP + c] = t.x;
      wT[(kc4 * 4 + 1) * LDP + c] = t.y;
      wT[(kc4 * 4 + 2) * LDP + c] = t.z;
      wT[(kc4 * 4 + 3) * LDP + c] = t.w;
    }
  }

  const int cg = tid & 15;  // column group: cols cg*4..cg*4+3
  const int rg = tid >> 4;  // row group:   rows rg*4..rg*4+3
  const float4 bv = reinterpret_cast<const float4*>(b)[cg];

  for (int tile = blockIdx.x; tile < ntiles; tile += gridDim.x) {
    const int row0 = tile * 64;
    const int nrows = min(64, n - row0);
    __syncthreads();  // prior-iter readers done (also publishes W on first iter)
    {
      const int r = r64;
      if (r < nrows) {
        const float4* xr = reinterpret_cast<const float4*>(x + (size_t)(row0 + r) * DDIM);
#pragma unroll
        for (int i = 0; i < 4; ++i) {
          const int kc4 = q * 4 + i;
          float4 t = xr[kc4];
          xT[(kc4 * 4 + 0) * LDP + r] = t.x;
          xT[(kc4 * 4 + 1) * LDP + r] = t.y;
          xT[(kc4 * 4 + 2) * LDP + r] = t.z;
          xT[(kc4 * 4 + 3) * LDP + r] = t.w;
        }
      }
    }
    __syncthreads();

    float acc[4][4];
#pragma unroll
    for (int i = 0; i < 4; ++i) {
      acc[i][0] = bv.x; acc[i][1] = bv.y; acc[i][2] = bv.z; acc[i][3] = bv.w;
    }
#pragma unroll 8
    for (int k = 0; k < 64; ++k) {
      const float4 xv = *reinterpret_cast<const float4*>(&xT[k * LDP + rg * 4]);
      const float4 wv = *reinterpret_cast<const float4*>(&wT[k * LDP + cg * 4]);
      const float xa[4] = {xv.x, xv.y, xv.z, xv.w};
      const float wa[4] = {wv.x, wv.y, wv.z, wv.w};
#pragma unroll
      for (int i = 0; i < 4; ++i)
#pragma unroll
        for (int j = 0; j < 4; ++j) acc[i][j] += xa[i] * wa[j];
    }
#pragma unroll
    for (int i = 0; i < 4; ++i) {
      const int r = rg * 4 + i;
      if (r < nrows) {
        float4 o = make_float4(acc[i][0], acc[i][1], acc[i][2], acc[i][3]);
        reinterpret_cast<float4*>(y + (size_t)(row0 + r) * DDIM)[cg] = o;
      }
    }
  }
}

// ---------------- Gather aggregation (wave per node, lane = dim) ----------------
// out[n] = (sum_{j in seg} lin_other[lists[j]] + lin_self[n]) / (deg + 1)
// offs is the POST-FILL array: segment g spans [offs[g-1], offs[g]) (offs[-1]==0).
__global__ __launch_bounds__(256) void gather_kernel(
    const int* __restrict__ offs, const int* __restrict__ lists,
    const float* __restrict__ lin_self, const float* __restrict__ lin_other,
    float* __restrict__ out, int n, int obase) {
  const int lane = threadIdx.x & 63;
  const int node = blockIdx.x * 4 + (threadIdx.x >> 6);
  if (node >= n) return;
  const int g = obase + node;
  const int start = (g == 0) ? 0 : offs[g - 1];
  const int end = offs[g];
  float acc = lin_self[(size_t)node * DDIM + lane];
  for (int j = start; j < end; ++j) {
    const int other = lists[j];
    acc += lin_other[(size_t)other * DDIM + lane];
  }
  out[(size_t)node * DDIM + lane] = acc / (float)(end - start + 1);
}

// ---------------- Launch ----------------

extern "C" void kernel_launch(void* const* d_in, const int* in_sizes, int n_in,
                              void* d_out, int out_size, void* d_ws,
                              size_t ws_size, hipStream_t stream) {
  const float* x_user = (const float*)d_in[0];
  const float* x_event = (const float*)d_in[1];
  const int* src = (const int*)d_in[2];
  const int* dst = (const int*)d_in[3];
  const float* Wu0 = (const float*)d_in[4];
  const float* bu0 = (const float*)d_in[5];
  const float* We0 = (const float*)d_in[6];
  const float* be0 = (const float*)d_in[7];
  const float* Wu1 = (const float*)d_in[8];
  const float* bu1 = (const float*)d_in[9];
  const float* We1 = (const float*)d_in[10];
  const float* be1 = (const float*)d_in[11];

  float* ws = (float*)d_ws;
  float* lin_u = ws;                                   // 12.8M floats
  float* lin_e = lin_u + (size_t)NUM_USER * DDIM;      // 3.2M floats
  int* offs = (int*)(lin_e + (size_t)NUM_EVENT * DDIM);  // 250000 ints
  int* bsums = offs + (NUM_USER + NUM_EVENT);            // 256 ints
  int* lists = bsums + 256;                              // 2,000,000 ints

  float* out_u = (float*)d_out;
  float* out_e = out_u + (size_t)NUM_USER * DDIM;

  const int NSEG = NUM_USER + NUM_EVENT;  // 250000
  const int nb = (NSEG + 2047) / 2048;    // 123 scan blocks

  // --- CSR build (shared by both layers) ---
  hipMemsetAsync(offs, 0, NSEG * sizeof(int), stream);
  histogram_kernel<<<(NUM_EDGES + 255) / 256, 256, 0, stream>>>(src, dst, offs, NUM_EDGES);
  scan_local_kernel<<<nb, 256, 0, stream>>>(offs, bsums, NSEG);
  scan_bsums_kernel<<<1, 256, 0, stream>>>(bsums, nb);
  scan_add_kernel<<<nb, 256, 0, stream>>>(offs, bsums, NSEG);
  fill_kernel<<<(NUM_EDGES + 255) / 256, 256, 0, stream>>>(src, dst, offs, lists, NUM_EDGES);

  const int tiles_u = (NUM_USER + 63) / 64;   // 3125
  const int tiles_e = (NUM_EVENT + 63) / 64;  // 782
  const int lgrid_u = 1024;
  const int lgrid_e = 782;
  const int ggrid_u = (NUM_USER + 3) / 4;   // 50000
  const int ggrid_e = (NUM_EVENT + 3) / 4;  // 12500

  // ---- Layer 1 ----
  linear_tiled_kernel<<<lgrid_u, 256, 0, stream>>>(x_user, Wu0, bu0, lin_u, NUM_USER, tiles_u);
  linear_tiled_kernel<<<lgrid_e, 256, 0, stream>>>(x_event, We0, be0, lin_e, NUM_EVENT, tiles_e);
  gather_kernel<<<ggrid_u, 256, 0, stream>>>(offs, lists, lin_u, lin_e, out_u, NUM_USER, 0);
  gather_kernel<<<ggrid_e, 256, 0, stream>>>(offs, lists, lin_e, lin_u, out_e, NUM_EVENT, NUM_USER);

  // ---- Layer 2 (reads d_out, writes lin buffers, then back to d_out) ----
  linear_tiled_kernel<<<lgrid_u, 256, 0, stream>>>(out_u, Wu1, bu1, lin_u, NUM_USER, tiles_u);
  linear_tiled_kernel<<<lgrid_e, 256, 0, stream>>>(out_e, We1, be1, lin_e, NUM_EVENT, tiles_e);
  gather_kernel<<<ggrid_u, 256, 0, stream>>>(offs, lists, lin_u, lin_e, out_u, NUM_USER, 0);
  gather_kernel<<<ggrid_e, 256, 0, stream>>>(offs, lists, lin_e, lin_u, out_e, NUM_EVENT, NUM_USER);
}

// Round 3
// 635.666 us; speedup vs baseline: 2.2817x; 1.3605x over previous
//
#include <hip/hip_runtime.h>

#define NUM_USER 200000
#define NUM_EVENT 50000
#define NUM_EDGES 1000000
#define DDIM 64
#define LDP 68  // LDS leading dim: 64+4 keeps 16B alignment; stride-68 banks are 2-way max (free)

// bf16 pair packing: lin tables are stored as uint = (bf16(hi)<<16)|bf16(lo),
// i.e. dims (2k, 2k+1) per uint. Unpack is 2 VALU ops (shift / mask).
__device__ __forceinline__ unsigned int pack_bf2(float lo, float hi) {
  unsigned int ul = __float_as_uint(lo);
  unsigned int uh = __float_as_uint(hi);
  ul = (ul + 0x7FFFu + ((ul >> 16) & 1u)) >> 16;
  uh = (uh + 0x7FFFu + ((uh >> 16) & 1u)) & 0xFFFF0000u;
  return uh | ul;
}
__device__ __forceinline__ float bf_lo(unsigned int v) {
  return __uint_as_float(v << 16);
}
__device__ __forceinline__ float bf_hi(unsigned int v) {
  return __uint_as_float(v & 0xFFFF0000u);
}

// ---------------- CSR build ----------------

__global__ __launch_bounds__(256) void histogram_kernel(
    const int* __restrict__ src, const int* __restrict__ dst,
    int* __restrict__ cnt, int E) {
  int i = blockIdx.x * blockDim.x + threadIdx.x;
  if (i < E) {
    atomicAdd(&cnt[dst[i]], 1);
    atomicAdd(&cnt[NUM_USER + src[i]], 1);
  }
}

// Exclusive scan, 2048 elements per block (256 threads x 8).
__global__ __launch_bounds__(256) void scan_local_kernel(
    int* __restrict__ data, int* __restrict__ bsums, int N) {
  __shared__ int sdata[256];
  const int tid = threadIdx.x;
  const int base = blockIdx.x * 2048 + tid * 8;
  int v[8];
  int s = 0;
#pragma unroll
  for (int j = 0; j < 8; ++j) {
    v[j] = (base + j < N) ? data[base + j] : 0;
    s += v[j];
  }
  sdata[tid] = s;
  __syncthreads();
  for (int off = 1; off < 256; off <<= 1) {
    int t = (tid >= off) ? sdata[tid - off] : 0;
    __syncthreads();
    sdata[tid] += t;
    __syncthreads();
  }
  if (tid == 255) bsums[blockIdx.x] = sdata[255];
  int run = (tid == 0) ? 0 : sdata[tid - 1];
#pragma unroll
  for (int j = 0; j < 8; ++j) {
    int t = v[j];
    if (base + j < N) data[base + j] = run;
    run += t;
  }
}

__global__ __launch_bounds__(256) void scan_bsums_kernel(int* __restrict__ bsums, int nb) {
  __shared__ int sdata[256];
  const int tid = threadIdx.x;
  int s = (tid < nb) ? bsums[tid] : 0;
  sdata[tid] = s;
  __syncthreads();
  for (int off = 1; off < 256; off <<= 1) {
    int t = (tid >= off) ? sdata[tid - off] : 0;
    __syncthreads();
    sdata[tid] += t;
    __syncthreads();
  }
  if (tid < nb) bsums[tid] = sdata[tid] - s;  // exclusive
}

__global__ __launch_bounds__(256) void scan_add_kernel(
    int* __restrict__ data, const int* __restrict__ bsums, int N) {
  const int base = blockIdx.x * 2048 + threadIdx.x * 8;
  const int add = bsums[blockIdx.x];
#pragma unroll
  for (int j = 0; j < 8; ++j) {
    if (base + j < N) data[base + j] += add;
  }
}

// User segments occupy positions [0, NUM_EDGES) (sum of user degrees == E),
// event segments [NUM_EDGES, 2*NUM_EDGES). User-list values are event ids
// (< 50000) -> u16. Non-temporal: these scattered lines have zero reuse in L2.
__global__ __launch_bounds__(256) void fill_kernel(
    const int* __restrict__ src, const int* __restrict__ dst,
    int* __restrict__ offs, unsigned short* __restrict__ lists_u,
    int* __restrict__ lists_e, int E) {
  int i = blockIdx.x * blockDim.x + threadIdx.x;
  if (i < E) {
    const int s = src[i];
    const int d = dst[i];
    int pu = atomicAdd(&offs[d], 1);
    __builtin_nontemporal_store((unsigned short)s, &lists_u[pu]);
    int pe = atomicAdd(&offs[NUM_USER + s], 1);
    __builtin_nontemporal_store(d, &lists_e[pe - NUM_EDGES]);
  }
}

// ---------------- Linear: y = x @ W^T + b, fp32 in, bf16-packed out ----------------

__global__ __launch_bounds__(256) void linear_tiled_kernel(
    const float* __restrict__ x, const float* __restrict__ W,
    const float* __restrict__ b, unsigned int* __restrict__ y, int n, int ntiles) {
  __shared__ float xT[64 * LDP];  // xT[k][r]
  __shared__ float wT[64 * LDP];  // wT[k][c] = W[c][k]
  const int tid = threadIdx.x;
  const int r64 = tid & 63;
  const int q = tid >> 6;

  {  // Stage W^T once per block.
    const int c = r64;
    const float4* wr = reinterpret_cast<const float4*>(W + (size_t)c * DDIM);
#pragma unroll
    for (int i = 0; i < 4; ++i) {
      const int kc4 = q * 4 + i;
      float4 t = wr[kc4];
      wT[(kc4 * 4 + 0) * LDP + c] = t.x;
      wT[(kc4 * 4 + 1) * LDP + c] = t.y;
      wT[(kc4 * 4 + 2) * LDP + c] = t.z;
      wT[(kc4 * 4 + 3) * LDP + c] = t.w;
    }
  }

  const int cg = tid & 15;  // cols cg*4..cg*4+3
  const int rg = tid >> 4;  // rows rg*4..rg*4+3
  const float4 bv = reinterpret_cast<const float4*>(b)[cg];

  for (int tile = blockIdx.x; tile < ntiles; tile += gridDim.x) {
    const int row0 = tile * 64;
    const int nrows = min(64, n - row0);
    __syncthreads();  // prior-iter readers done (also publishes W on first iter)
    {
      const int r = r64;
      if (r < nrows) {
        const float4* xr = reinterpret_cast<const float4*>(x + (size_t)(row0 + r) * DDIM);
#pragma unroll
        for (int i = 0; i < 4; ++i) {
          const int kc4 = q * 4 + i;
          float4 t = xr[kc4];
          xT[(kc4 * 4 + 0) * LDP + r] = t.x;
          xT[(kc4 * 4 + 1) * LDP + r] = t.y;
          xT[(kc4 * 4 + 2) * LDP + r] = t.z;
          xT[(kc4 * 4 + 3) * LDP + r] = t.w;
        }
      }
    }
    __syncthreads();

    float acc[4][4];
#pragma unroll
    for (int i = 0; i < 4; ++i) {
      acc[i][0] = bv.x; acc[i][1] = bv.y; acc[i][2] = bv.z; acc[i][3] = bv.w;
    }
#pragma unroll 8
    for (int k = 0; k < 64; ++k) {
      const float4 xv = *reinterpret_cast<const float4*>(&xT[k * LDP + rg * 4]);
      const float4 wv = *reinterpret_cast<const float4*>(&wT[k * LDP + cg * 4]);
      const float xa[4] = {xv.x, xv.y, xv.z, xv.w};
      const float wa[4] = {wv.x, wv.y, wv.z, wv.w};
#pragma unroll
      for (int i = 0; i < 4; ++i)
#pragma unroll
        for (int j = 0; j < 4; ++j) acc[i][j] += xa[i] * wa[j];
    }
#pragma unroll
    for (int i = 0; i < 4; ++i) {
      const int r = rg * 4 + i;
      if (r < nrows) {
        uint2 o = make_uint2(pack_bf2(acc[i][0], acc[i][1]),
                             pack_bf2(acc[i][2], acc[i][3]));
        reinterpret_cast<uint2*>(y + (size_t)(row0 + r) * 32)[cg] = o;
      }
    }
  }
}

// ---------------- Gather aggregation ----------------
// 2 nodes per wave: lanes 0-31 node A, 32-63 node B; lane = dim pair (uint of
// 2 bf16). out[n] = (sum_neighbors lin_other[nb] + lin_self[n]) / (deg+1).
// offs is POST-FILL: segment g spans [offs[g-1], offs[g]).
template <typename IdxT>
__global__ __launch_bounds__(256) void gather_kernel(
    const int* __restrict__ offs, const IdxT* __restrict__ lists,
    const unsigned int* __restrict__ lin_self,
    const unsigned int* __restrict__ lin_other, float* __restrict__ out,
    int n, int obase, int lbase) {
  const int lane = threadIdx.x & 63;
  const int sub = lane >> 5;
  const int dl = lane & 31;
  const int wave = blockIdx.x * (blockDim.x >> 6) + (threadIdx.x >> 6);
  const int node = wave * 2 + sub;
  if (node >= n) return;
  const int g = obase + node;
  const int start = (g == 0) ? 0 : offs[g - 1];
  const int end = offs[g];

  const unsigned int sv = lin_self[(size_t)node * 32 + dl];
  float ax = bf_lo(sv), ay = bf_hi(sv);

  int j = start;
  for (; j + 2 <= end; j += 2) {
    const int o0 = (int)lists[j - lbase];
    const int o1 = (int)lists[j + 1 - lbase];
    const unsigned int v0 = lin_other[(size_t)o0 * 32 + dl];
    const unsigned int v1 = lin_other[(size_t)o1 * 32 + dl];
    ax += bf_lo(v0); ay += bf_hi(v0);
    ax += bf_lo(v1); ay += bf_hi(v1);
  }
  if (j < end) {
    const int o0 = (int)lists[j - lbase];
    const unsigned int v0 = lin_other[(size_t)o0 * 32 + dl];
    ax += bf_lo(v0); ay += bf_hi(v0);
  }
  const float inv = 1.0f / (float)(end - start + 1);
  reinterpret_cast<float2*>(out)[(size_t)node * 32 + dl] =
      make_float2(ax * inv, ay * inv);
}

// ---------------- Launch ----------------

extern "C" void kernel_launch(void* const* d_in, const int* in_sizes, int n_in,
                              void* d_out, int out_size, void* d_ws,
                              size_t ws_size, hipStream_t stream) {
  const float* x_user = (const float*)d_in[0];
  const float* x_event = (const float*)d_in[1];
  const int* src = (const int*)d_in[2];
  const int* dst = (const int*)d_in[3];
  const float* Wu0 = (const float*)d_in[4];
  const float* bu0 = (const float*)d_in[5];
  const float* We0 = (const float*)d_in[6];
  const float* be0 = (const float*)d_in[7];
  const float* Wu1 = (const float*)d_in[8];
  const float* bu1 = (const float*)d_in[9];
  const float* We1 = (const float*)d_in[10];
  const float* be1 = (const float*)d_in[11];

  unsigned int* lin_u = (unsigned int*)d_ws;                 // 6.4M uints (25.6 MB)
  unsigned int* lin_e = lin_u + (size_t)NUM_USER * 32;       // 1.6M uints (6.4 MB)
  int* offs = (int*)(lin_e + (size_t)NUM_EVENT * 32);        // 250,000 ints
  int* bsums = offs + (NUM_USER + NUM_EVENT);                // 256 ints
  int* lists_e = bsums + 256;                                // 1M ints (4 MB)
  unsigned short* lists_u = (unsigned short*)(lists_e + NUM_EDGES);  // 1M u16 (2 MB)

  float* out_u = (float*)d_out;
  float* out_e = out_u + (size_t)NUM_USER * DDIM;

  const int NSEG = NUM_USER + NUM_EVENT;  // 250000
  const int nb = (NSEG + 2047) / 2048;    // 123 scan blocks

  // --- CSR build (shared by both layers) ---
  hipMemsetAsync(offs, 0, NSEG * sizeof(int), stream);
  histogram_kernel<<<(NUM_EDGES + 255) / 256, 256, 0, stream>>>(src, dst, offs, NUM_EDGES);
  scan_local_kernel<<<nb, 256, 0, stream>>>(offs, bsums, NSEG);
  scan_bsums_kernel<<<1, 256, 0, stream>>>(bsums, nb);
  scan_add_kernel<<<nb, 256, 0, stream>>>(offs, bsums, NSEG);
  fill_kernel<<<(NUM_EDGES + 255) / 256, 256, 0, stream>>>(src, dst, offs, lists_u,
                                                           lists_e, NUM_EDGES);

  const int tiles_u = (NUM_USER + 63) / 64;   // 3125
  const int tiles_e = (NUM_EVENT + 63) / 64;  // 782
  const int lgrid_u = 1024;
  const int lgrid_e = 782;
  const int ggrid_u = (NUM_USER + 7) / 8;   // 25000 (8 nodes per block)
  const int ggrid_e = (NUM_EVENT + 7) / 8;  // 6250

  // ---- Layer 1 ----
  linear_tiled_kernel<<<lgrid_u, 256, 0, stream>>>(x_user, Wu0, bu0, lin_u, NUM_USER, tiles_u);
  linear_tiled_kernel<<<lgrid_e, 256, 0, stream>>>(x_event, We0, be0, lin_e, NUM_EVENT, tiles_e);
  gather_kernel<unsigned short><<<ggrid_u, 256, 0, stream>>>(
      offs, lists_u, lin_u, lin_e, out_u, NUM_USER, 0, 0);
  gather_kernel<int><<<ggrid_e, 256, 0, stream>>>(
      offs, lists_e, lin_e, lin_u, out_e, NUM_EVENT, NUM_USER, NUM_EDGES);

  // ---- Layer 2 (reads d_out fp32, stages bf16, writes back to d_out) ----
  linear_tiled_kernel<<<lgrid_u, 256, 0, stream>>>(out_u, Wu1, bu1, lin_u, NUM_USER, tiles_u);
  linear_tiled_kernel<<<lgrid_e, 256, 0, stream>>>(out_e, We1, be1, lin_e, NUM_EVENT, tiles_e);
  gather_kernel<unsigned short><<<ggrid_u, 256, 0, stream>>>(
      offs, lists_u, lin_u, lin_e, out_u, NUM_USER, 0, 0);
  gather_kernel<int><<<ggrid_e, 256, 0, stream>>>(
      offs, lists_e, lin_e, lin_u, out_e, NUM_EVENT, NUM_USER, NUM_EDGES);
}

// Round 4
// 460.367 us; speedup vs baseline: 3.1506x; 1.3808x over previous
//
#include <hip/hip_runtime.h>

#define NUM_USER 200000
#define NUM_EVENT 50000
#define NUM_EDGES 1000000
#define DDIM 64
#define LDP 68  // LDS leading dim for linear tiles

// Bucketed CSR build: user buckets span 2048 nodes, event buckets span 256.
#define NBU 98                 // 98*2048 = 200704 >= NUM_USER
#define NBE 196                // 196*256 = 50176 >= NUM_EVENT
#define NB (NBU + NBE)         // 294
#define CHUNK 8192
#define NCH ((NUM_EDGES + CHUNK - 1) / CHUNK)  // 123

// bf16 pair packing: lin tables stored as uint = (bf16(hi)<<16)|bf16(lo).
__device__ __forceinline__ unsigned int pack_bf2(float lo, float hi) {
  unsigned int ul = __float_as_uint(lo);
  unsigned int uh = __float_as_uint(hi);
  ul = (ul + 0x7FFFu + ((ul >> 16) & 1u)) >> 16;
  uh = (uh + 0x7FFFu + ((uh >> 16) & 1u)) & 0xFFFF0000u;
  return uh | ul;
}
__device__ __forceinline__ float bf_lo(unsigned int v) { return __uint_as_float(v << 16); }
__device__ __forceinline__ float bf_hi(unsigned int v) { return __uint_as_float(v & 0xFFFF0000u); }

// ---------------- CSR build: pass A (bucket histogram) ----------------

__global__ __launch_bounds__(256) void bucket_count_kernel(
    const int* __restrict__ src, const int* __restrict__ dst,
    int* __restrict__ bc) {
  __shared__ int cnt[NB];
  for (int i = threadIdx.x; i < NB; i += 256) cnt[i] = 0;
  __syncthreads();
  const int e0 = blockIdx.x * CHUNK;
  const int e1 = min(e0 + CHUNK, NUM_EDGES);
  for (int i = e0 + threadIdx.x; i < e1; i += 256) {
    atomicAdd(&cnt[dst[i] >> 11], 1);
    atomicAdd(&cnt[NBU + (src[i] >> 8)], 1);
  }
  __syncthreads();
  for (int i = threadIdx.x; i < NB; i += 256)
    if (cnt[i]) atomicAdd(&bc[i], cnt[i]);
}

// Exclusive scan of 294 bucket counts; emits bucket bases (CSR positions) and
// per-bucket fill cursors (adjusted to index itemsU / itemsE directly).
__global__ __launch_bounds__(512) void bucket_scan_kernel(
    const int* __restrict__ bc, int* __restrict__ bbase, int* __restrict__ gcur) {
  __shared__ int s[512];
  const int tid = threadIdx.x;
  int v = (tid < NB) ? bc[tid] : 0;
  s[tid] = v;
  __syncthreads();
  for (int off = 1; off < 512; off <<= 1) {
    int t = (tid >= off) ? s[tid - off] : 0;
    __syncthreads();
    s[tid] += t;
    __syncthreads();
  }
  if (tid < NB) {
    int excl = s[tid] - v;
    bbase[tid] = excl;
    gcur[tid] = excl - ((tid >= NBU) ? NUM_EDGES : 0);
  }
  if (tid == 0) bbase[NB] = 2 * NUM_EDGES;
}

// Pass A2: scatter packed items into bucket-contiguous runs.
// itemU = (dst&2047)<<16 | src   (11+16 bits)
// itemE = (src&255)<<18  | dst   (8+18 bits)
__global__ __launch_bounds__(256) void bucket_scatter_kernel(
    const int* __restrict__ src, const int* __restrict__ dst,
    int* __restrict__ gcur, unsigned int* __restrict__ itemsU,
    unsigned int* __restrict__ itemsE) {
  __shared__ int cnt[NB];
  __shared__ int cur[NB];
  for (int i = threadIdx.x; i < NB; i += 256) cnt[i] = 0;
  __syncthreads();
  const int e0 = blockIdx.x * CHUNK;
  const int e1 = min(e0 + CHUNK, NUM_EDGES);
  for (int i = e0 + threadIdx.x; i < e1; i += 256) {
    atomicAdd(&cnt[dst[i] >> 11], 1);
    atomicAdd(&cnt[NBU + (src[i] >> 8)], 1);
  }
  __syncthreads();
  for (int i = threadIdx.x; i < NB; i += 256) {
    int c = cnt[i];
    cur[i] = c ? atomicAdd(&gcur[i], c) : 0;
  }
  __syncthreads();
  for (int i = e0 + threadIdx.x; i < e1; i += 256) {
    const int s = src[i];
    const int d = dst[i];
    int r = atomicAdd(&cur[d >> 11], 1);
    itemsU[r] = ((unsigned int)(d & 2047) << 16) | (unsigned int)s;
    int r2 = atomicAdd(&cur[NBU + (s >> 8)], 1);
    itemsE[r2] = ((unsigned int)(s & 255) << 18) | (unsigned int)d;
  }
}

// Pass B (user): one block per bucket. Local per-node histogram + scan ->
// offs (END positions, coalesced), then value scatter confined to this
// bucket's <=~25 KB list region (single CU -> full L2 line merging).
__global__ __launch_bounds__(256) void build_user_kernel(
    const int* __restrict__ bbase, const unsigned int* __restrict__ itemsU,
    int* __restrict__ offs, unsigned short* __restrict__ lists_u) {
  __shared__ int cnt[2048];
  __shared__ int part[256];
  const int b = blockIdx.x;
  const int istart = bbase[b];
  const int iend = bbase[b + 1];
  const int tid = threadIdx.x;
  for (int i = tid; i < 2048; i += 256) cnt[i] = 0;
  __syncthreads();
  for (int i = istart + tid; i < iend; i += 256)
    atomicAdd(&cnt[itemsU[i] >> 16], 1);
  __syncthreads();
  int v[8];
  int sum = 0;
#pragma unroll
  for (int j = 0; j < 8; ++j) {
    v[j] = cnt[tid * 8 + j];
    sum += v[j];
  }
  part[tid] = sum;
  __syncthreads();
  for (int off = 1; off < 256; off <<= 1) {
    int t = (tid >= off) ? part[tid - off] : 0;
    __syncthreads();
    part[tid] += t;
    __syncthreads();
  }
  int run = (tid == 0) ? 0 : part[tid - 1];
  const int node0 = b * 2048;
#pragma unroll
  for (int j = 0; j < 8; ++j) {
    const int n = node0 + tid * 8 + j;
    if (n < NUM_USER) offs[n] = istart + run + v[j];  // END position
    cnt[tid * 8 + j] = run;                           // exclusive -> cursor
    run += v[j];
  }
  __syncthreads();
  for (int i = istart + tid; i < iend; i += 256) {
    const unsigned int it = itemsU[i];
    int r = atomicAdd(&cnt[it >> 16], 1);
    lists_u[istart + r] = (unsigned short)(it & 0xFFFFu);
  }
}

// Pass B (event): one block per bucket of 256 events.
__global__ __launch_bounds__(256) void build_event_kernel(
    const int* __restrict__ bbase, const unsigned int* __restrict__ itemsE,
    int* __restrict__ offs, int* __restrict__ lists_e) {
  __shared__ int cnt[256];
  __shared__ int s2[256];
  const int b = blockIdx.x;
  const int istart = bbase[NBU + b] - NUM_EDGES;
  const int iend = bbase[NBU + b + 1] - NUM_EDGES;
  const int tid = threadIdx.x;
  cnt[tid] = 0;
  __syncthreads();
  for (int i = istart + tid; i < iend; i += 256)
    atomicAdd(&cnt[itemsE[i] >> 18], 1);
  __syncthreads();
  const int v = cnt[tid];
  s2[tid] = v;
  __syncthreads();
  for (int off = 1; off < 256; off <<= 1) {
    int t = (tid >= off) ? s2[tid - off] : 0;
    __syncthreads();
    s2[tid] += t;
    __syncthreads();
  }
  const int excl = s2[tid] - v;
  const int e0 = b * 256;
  if (e0 + tid < NUM_EVENT)
    offs[NUM_USER + e0 + tid] = NUM_EDGES + istart + excl + v;  // END position
  cnt[tid] = excl;
  __syncthreads();
  for (int i = istart + tid; i < iend; i += 256) {
    const unsigned int it = itemsE[i];
    int r = atomicAdd(&cnt[it >> 18], 1);
    lists_e[istart + r] = (int)(it & 0x3FFFFu);
  }
}

// ---------------- Linear: y = x @ W^T + b, fp32 in, bf16-packed out ----------------

__global__ __launch_bounds__(256) void linear_tiled_kernel(
    const float* __restrict__ x, const float* __restrict__ W,
    const float* __restrict__ b, unsigned int* __restrict__ y, int n, int ntiles) {
  __shared__ float xT[64 * LDP];  // xT[k][r]
  __shared__ float wT[64 * LDP];  // wT[k][c] = W[c][k]
  const int tid = threadIdx.x;
  const int r64 = tid & 63;
  const int q = tid >> 6;

  {  // Stage W^T once per block.
    const int c = r64;
    const float4* wr = reinterpret_cast<const float4*>(W + (size_t)c * DDIM);
#pragma unroll
    for (int i = 0; i < 4; ++i) {
      const int kc4 = q * 4 + i;
      float4 t = wr[kc4];
      wT[(kc4 * 4 + 0) * LDP + c] = t.x;
      wT[(kc4 * 4 + 1) * LDP + c] = t.y;
      wT[(kc4 * 4 + 2) * LDP + c] = t.z;
      wT[(kc4 * 4 + 3) * LDP + c] = t.w;
    }
  }

  const int cg = tid & 15;  // cols cg*4..cg*4+3
  const int rg = tid >> 4;  // rows rg*4..rg*4+3
  const float4 bv = reinterpret_cast<const float4*>(b)[cg];

  for (int tile = blockIdx.x; tile < ntiles; tile += gridDim.x) {
    const int row0 = tile * 64;
    const int nrows = min(64, n - row0);
    __syncthreads();  // prior-iter readers done (also publishes W on first iter)
    {
      const int r = r64;
      if (r < nrows) {
        const float4* xr = reinterpret_cast<const float4*>(x + (size_t)(row0 + r) * DDIM);
#pragma unroll
        for (int i = 0; i < 4; ++i) {
          const int kc4 = q * 4 + i;
          float4 t = xr[kc4];
          xT[(kc4 * 4 + 0) * LDP + r] = t.x;
          xT[(kc4 * 4 + 1) * LDP + r] = t.y;
          xT[(kc4 * 4 + 2) * LDP + r] = t.z;
          xT[(kc4 * 4 + 3) * LDP + r] = t.w;
        }
      }
    }
    __syncthreads();

    float acc[4][4];
#pragma unroll
    for (int i = 0; i < 4; ++i) {
      acc[i][0] = bv.x; acc[i][1] = bv.y; acc[i][2] = bv.z; acc[i][3] = bv.w;
    }
#pragma unroll 8
    for (int k = 0; k < 64; ++k) {
      const float4 xv = *reinterpret_cast<const float4*>(&xT[k * LDP + rg * 4]);
      const float4 wv = *reinterpret_cast<const float4*>(&wT[k * LDP + cg * 4]);
      const float xa[4] = {xv.x, xv.y, xv.z, xv.w};
      const float wa[4] = {wv.x, wv.y, wv.z, wv.w};
#pragma unroll
      for (int i = 0; i < 4; ++i)
#pragma unroll
        for (int j = 0; j < 4; ++j) acc[i][j] += xa[i] * wa[j];
    }
#pragma unroll
    for (int i = 0; i < 4; ++i) {
      const int r = rg * 4 + i;
      if (r < nrows) {
        uint2 o = make_uint2(pack_bf2(acc[i][0], acc[i][1]),
                             pack_bf2(acc[i][2], acc[i][3]));
        reinterpret_cast<uint2*>(y + (size_t)(row0 + r) * 32)[cg] = o;
      }
    }
  }
}

// ---------------- Gather aggregation ----------------
// 2 nodes per wave; lane = dim pair. offs is END-position array:
// segment g spans [offs[g-1], offs[g]) with offs[-1] == 0.
template <typename IdxT>
__global__ __launch_bounds__(256) void gather_kernel(
    const int* __restrict__ offs, const IdxT* __restrict__ lists,
    const unsigned int* __restrict__ lin_self,
    const unsigned int* __restrict__ lin_other, float* __restrict__ out,
    int n, int obase, int lbase) {
  const int lane = threadIdx.x & 63;
  const int sub = lane >> 5;
  const int dl = lane & 31;
  const int wave = blockIdx.x * (blockDim.x >> 6) + (threadIdx.x >> 6);
  const int node = wave * 2 + sub;
  if (node >= n) return;
  const int g = obase + node;
  const int start = (g == 0) ? 0 : offs[g - 1];
  const int end = offs[g];

  const unsigned int sv = lin_self[(size_t)node * 32 + dl];
  float ax = bf_lo(sv), ay = bf_hi(sv);

  int j = start;
  for (; j + 2 <= end; j += 2) {
    const int o0 = (int)lists[j - lbase];
    const int o1 = (int)lists[j + 1 - lbase];
    const unsigned int v0 = lin_other[(size_t)o0 * 32 + dl];
    const unsigned int v1 = lin_other[(size_t)o1 * 32 + dl];
    ax += bf_lo(v0); ay += bf_hi(v0);
    ax += bf_lo(v1); ay += bf_hi(v1);
  }
  if (j < end) {
    const int o0 = (int)lists[j - lbase];
    const unsigned int v0 = lin_other[(size_t)o0 * 32 + dl];
    ax += bf_lo(v0); ay += bf_hi(v0);
  }
  const float inv = 1.0f / (float)(end - start + 1);
  reinterpret_cast<float2*>(out)[(size_t)node * 32 + dl] =
      make_float2(ax * inv, ay * inv);
}

// ---------------- Launch ----------------

extern "C" void kernel_launch(void* const* d_in, const int* in_sizes, int n_in,
                              void* d_out, int out_size, void* d_ws,
                              size_t ws_size, hipStream_t stream) {
  const float* x_user = (const float*)d_in[0];
  const float* x_event = (const float*)d_in[1];
  const int* src = (const int*)d_in[2];
  const int* dst = (const int*)d_in[3];
  const float* Wu0 = (const float*)d_in[4];
  const float* bu0 = (const float*)d_in[5];
  const float* We0 = (const float*)d_in[6];
  const float* be0 = (const float*)d_in[7];
  const float* Wu1 = (const float*)d_in[8];
  const float* bu1 = (const float*)d_in[9];
  const float* We1 = (const float*)d_in[10];
  const float* be1 = (const float*)d_in[11];

  unsigned int* lin_u = (unsigned int*)d_ws;            // 6.4M u32
  unsigned int* lin_e = lin_u + (size_t)NUM_USER * 32;  // 1.6M u32
  int* offs = (int*)(lin_e + (size_t)NUM_EVENT * 32);   // 250,000
  int* bc = offs + (NUM_USER + NUM_EVENT);              // 294
  int* bbase = bc + NB;                                 // 295
  int* gcur = bbase + NB + 1;                           // 294
  unsigned int* itemsU = (unsigned int*)(gcur + NB);    // 1M
  unsigned int* itemsE = itemsU + NUM_EDGES;            // 1M
  int* lists_e = (int*)(itemsE + NUM_EDGES);            // 1M int
  unsigned short* lists_u = (unsigned short*)(lists_e + NUM_EDGES);  // 1M u16

  float* out_u = (float*)d_out;
  float* out_e = out_u + (size_t)NUM_USER * DDIM;

  // --- CSR build (bucketed counting sort; shared by both layers) ---
  hipMemsetAsync(bc, 0, NB * sizeof(int), stream);
  bucket_count_kernel<<<NCH, 256, 0, stream>>>(src, dst, bc);
  bucket_scan_kernel<<<1, 512, 0, stream>>>(bc, bbase, gcur);
  bucket_scatter_kernel<<<NCH, 256, 0, stream>>>(src, dst, gcur, itemsU, itemsE);
  build_user_kernel<<<NBU, 256, 0, stream>>>(bbase, itemsU, offs, lists_u);
  build_event_kernel<<<NBE, 256, 0, stream>>>(bbase, itemsE, offs, lists_e);

  const int tiles_u = (NUM_USER + 63) / 64;   // 3125
  const int tiles_e = (NUM_EVENT + 63) / 64;  // 782
  const int lgrid_u = 1024;
  const int lgrid_e = 782;
  const int ggrid_u = (NUM_USER + 7) / 8;   // 25000
  const int ggrid_e = (NUM_EVENT + 7) / 8;  // 6250

  // ---- Layer 1 ----
  linear_tiled_kernel<<<lgrid_u, 256, 0, stream>>>(x_user, Wu0, bu0, lin_u, NUM_USER, tiles_u);
  linear_tiled_kernel<<<lgrid_e, 256, 0, stream>>>(x_event, We0, be0, lin_e, NUM_EVENT, tiles_e);
  gather_kernel<unsigned short><<<ggrid_u, 256, 0, stream>>>(
      offs, lists_u, lin_u, lin_e, out_u, NUM_USER, 0, 0);
  gather_kernel<int><<<ggrid_e, 256, 0, stream>>>(
      offs, lists_e, lin_e, lin_u, out_e, NUM_EVENT, NUM_USER, NUM_EDGES);

  // ---- Layer 2 ----
  linear_tiled_kernel<<<lgrid_u, 256, 0, stream>>>(out_u, Wu1, bu1, lin_u, NUM_USER, tiles_u);
  linear_tiled_kernel<<<lgrid_e, 256, 0, stream>>>(out_e, We1, be1, lin_e, NUM_EVENT, tiles_e);
  gather_kernel<unsigned short><<<ggrid_u, 256, 0, stream>>>(
      offs, lists_u, lin_u, lin_e, out_u, NUM_USER, 0, 0);
  gather_kernel<int><<<ggrid_e, 256, 0, stream>>>(
      offs, lists_e, lin_e, lin_u, out_e, NUM_EVENT, NUM_USER, NUM_EDGES);
}

// Round 5
// 437.260 us; speedup vs baseline: 3.3171x; 1.0528x over previous
//
#include <hip/hip_runtime.h>

#define NUM_USER 200000
#define NUM_EVENT 50000
#define NUM_EDGES 1000000
#define DDIM 64
#define LDP 68  // LDS leading dim for linear tiles

// Bucketed CSR build: user buckets span 2048 nodes, event buckets span 256.
#define NBU 98                 // 98*2048 = 200704 >= NUM_USER
#define NBE 196                // 196*256 = 50176 >= NUM_EVENT
#define NB (NBU + NBE)         // 294
#define CHUNK 8192
#define NCH ((NUM_EDGES + CHUNK - 1) / CHUNK)  // 123

// Fused-kernel grid splits
#define LGU 1024   // linear: user-tile blocks
#define LGE 256    // linear: event-tile blocks
#define GGU 1536   // gather: user blocks
#define GGE 512    // gather: event blocks  (GGU+GGE = 2048 blocks = 8192 waves = capacity)

// bf16 pair packing: lin tables stored as uint = (bf16(hi)<<16)|bf16(lo).
__device__ __forceinline__ unsigned int pack_bf2(float lo, float hi) {
  unsigned int ul = __float_as_uint(lo);
  unsigned int uh = __float_as_uint(hi);
  ul = (ul + 0x7FFFu + ((ul >> 16) & 1u)) >> 16;
  uh = (uh + 0x7FFFu + ((uh >> 16) & 1u)) & 0xFFFF0000u;
  return uh | ul;
}
__device__ __forceinline__ float bf_lo(unsigned int v) { return __uint_as_float(v << 16); }
__device__ __forceinline__ float bf_hi(unsigned int v) { return __uint_as_float(v & 0xFFFF0000u); }

// ---------------- CSR build: pass A (bucket histogram) ----------------

__global__ __launch_bounds__(256) void bucket_count_kernel(
    const int* __restrict__ src, const int* __restrict__ dst,
    int* __restrict__ bc) {
  __shared__ int cnt[NB];
  for (int i = threadIdx.x; i < NB; i += 256) cnt[i] = 0;
  __syncthreads();
  const int e0 = blockIdx.x * CHUNK;
  const int e1 = min(e0 + CHUNK, NUM_EDGES);
  for (int i = e0 + threadIdx.x; i < e1; i += 256) {
    atomicAdd(&cnt[dst[i] >> 11], 1);
    atomicAdd(&cnt[NBU + (src[i] >> 8)], 1);
  }
  __syncthreads();
  for (int i = threadIdx.x; i < NB; i += 256)
    if (cnt[i]) atomicAdd(&bc[i], cnt[i]);
}

__global__ __launch_bounds__(512) void bucket_scan_kernel(
    const int* __restrict__ bc, int* __restrict__ bbase, int* __restrict__ gcur) {
  __shared__ int s[512];
  const int tid = threadIdx.x;
  int v = (tid < NB) ? bc[tid] : 0;
  s[tid] = v;
  __syncthreads();
  for (int off = 1; off < 512; off <<= 1) {
    int t = (tid >= off) ? s[tid - off] : 0;
    __syncthreads();
    s[tid] += t;
    __syncthreads();
  }
  if (tid < NB) {
    int excl = s[tid] - v;
    bbase[tid] = excl;
    gcur[tid] = excl - ((tid >= NBU) ? NUM_EDGES : 0);
  }
  if (tid == 0) bbase[NB] = 2 * NUM_EDGES;
}

// Pass A2: scatter packed items into bucket-contiguous runs.
// itemU = (dst&2047)<<16 | src ; itemE = (src&255)<<18 | dst
__global__ __launch_bounds__(256) void bucket_scatter_kernel(
    const int* __restrict__ src, const int* __restrict__ dst,
    int* __restrict__ gcur, unsigned int* __restrict__ itemsU,
    unsigned int* __restrict__ itemsE) {
  __shared__ int cnt[NB];
  __shared__ int cur[NB];
  for (int i = threadIdx.x; i < NB; i += 256) cnt[i] = 0;
  __syncthreads();
  const int e0 = blockIdx.x * CHUNK;
  const int e1 = min(e0 + CHUNK, NUM_EDGES);
  for (int i = e0 + threadIdx.x; i < e1; i += 256) {
    atomicAdd(&cnt[dst[i] >> 11], 1);
    atomicAdd(&cnt[NBU + (src[i] >> 8)], 1);
  }
  __syncthreads();
  for (int i = threadIdx.x; i < NB; i += 256) {
    int c = cnt[i];
    cur[i] = c ? atomicAdd(&gcur[i], c) : 0;
  }
  __syncthreads();
  for (int i = e0 + threadIdx.x; i < e1; i += 256) {
    const int s = src[i];
    const int d = dst[i];
    int r = atomicAdd(&cur[d >> 11], 1);
    itemsU[r] = ((unsigned int)(d & 2047) << 16) | (unsigned int)s;
    int r2 = atomicAdd(&cur[NBU + (s >> 8)], 1);
    itemsE[r2] = ((unsigned int)(s & 255) << 18) | (unsigned int)d;
  }
}

// Pass B (user): one block per bucket.
__global__ __launch_bounds__(256) void build_user_kernel(
    const int* __restrict__ bbase, const unsigned int* __restrict__ itemsU,
    int* __restrict__ offs, unsigned short* __restrict__ lists_u) {
  __shared__ int cnt[2048];
  __shared__ int part[256];
  const int b = blockIdx.x;
  const int istart = bbase[b];
  const int iend = bbase[b + 1];
  const int tid = threadIdx.x;
  for (int i = tid; i < 2048; i += 256) cnt[i] = 0;
  __syncthreads();
  for (int i = istart + tid; i < iend; i += 256)
    atomicAdd(&cnt[itemsU[i] >> 16], 1);
  __syncthreads();
  int v[8];
  int sum = 0;
#pragma unroll
  for (int j = 0; j < 8; ++j) {
    v[j] = cnt[tid * 8 + j];
    sum += v[j];
  }
  part[tid] = sum;
  __syncthreads();
  for (int off = 1; off < 256; off <<= 1) {
    int t = (tid >= off) ? part[tid - off] : 0;
    __syncthreads();
    part[tid] += t;
    __syncthreads();
  }
  int run = (tid == 0) ? 0 : part[tid - 1];
  const int node0 = b * 2048;
#pragma unroll
  for (int j = 0; j < 8; ++j) {
    const int n = node0 + tid * 8 + j;
    if (n < NUM_USER) offs[n] = istart + run + v[j];  // END position
    cnt[tid * 8 + j] = run;                           // exclusive -> cursor
    run += v[j];
  }
  __syncthreads();
  for (int i = istart + tid; i < iend; i += 256) {
    const unsigned int it = itemsU[i];
    int r = atomicAdd(&cnt[it >> 16], 1);
    lists_u[istart + r] = (unsigned short)(it & 0xFFFFu);
  }
}

// Pass B (event): one block per bucket of 256 events.
__global__ __launch_bounds__(256) void build_event_kernel(
    const int* __restrict__ bbase, const unsigned int* __restrict__ itemsE,
    int* __restrict__ offs, int* __restrict__ lists_e) {
  __shared__ int cnt[256];
  __shared__ int s2[256];
  const int b = blockIdx.x;
  const int istart = bbase[NBU + b] - NUM_EDGES;
  const int iend = bbase[NBU + b + 1] - NUM_EDGES;
  const int tid = threadIdx.x;
  cnt[tid] = 0;
  __syncthreads();
  for (int i = istart + tid; i < iend; i += 256)
    atomicAdd(&cnt[itemsE[i] >> 18], 1);
  __syncthreads();
  const int v = cnt[tid];
  s2[tid] = v;
  __syncthreads();
  for (int off = 1; off < 256; off <<= 1) {
    int t = (tid >= off) ? s2[tid - off] : 0;
    __syncthreads();
    s2[tid] += t;
    __syncthreads();
  }
  const int excl = s2[tid] - v;
  const int e0 = b * 256;
  if (e0 + tid < NUM_EVENT)
    offs[NUM_USER + e0 + tid] = NUM_EDGES + istart + excl + v;  // END position
  cnt[tid] = excl;
  __syncthreads();
  for (int i = istart + tid; i < iend; i += 256) {
    const unsigned int it = itemsE[i];
    int r = atomicAdd(&cnt[it >> 18], 1);
    lists_e[istart + r] = (int)(it & 0x3FFFFu);
  }
}

// ---------------- Fused linear: y = x @ W^T + b, fp32 in, bf16-packed out ----------------

__device__ __forceinline__ void linear_tiles(
    const float* __restrict__ x, const float* __restrict__ W,
    const float* __restrict__ b, unsigned int* __restrict__ y, int n,
    int ntiles, int bid, int nblocks) {
  __shared__ float xT[64 * LDP];  // xT[k][r]
  __shared__ float wT[64 * LDP];  // wT[k][c] = W[c][k]
  const int tid = threadIdx.x;
  const int r64 = tid & 63;
  const int q = tid >> 6;

  {  // Stage W^T once per block.
    const int c = r64;
    const float4* wr = reinterpret_cast<const float4*>(W + (size_t)c * DDIM);
#pragma unroll
    for (int i = 0; i < 4; ++i) {
      const int kc4 = q * 4 + i;
      float4 t = wr[kc4];
      wT[(kc4 * 4 + 0) * LDP + c] = t.x;
      wT[(kc4 * 4 + 1) * LDP + c] = t.y;
      wT[(kc4 * 4 + 2) * LDP + c] = t.z;
      wT[(kc4 * 4 + 3) * LDP + c] = t.w;
    }
  }

  const int cg = tid & 15;  // cols cg*4..cg*4+3
  const int rg = tid >> 4;  // rows rg*4..rg*4+3
  const float4 bv = reinterpret_cast<const float4*>(b)[cg];

  for (int tile = bid; tile < ntiles; tile += nblocks) {
    const int row0 = tile * 64;
    const int nrows = min(64, n - row0);
    __syncthreads();  // prior-iter readers done (also publishes W on first iter)
    {
      const int r = r64;
      if (r < nrows) {
        const float4* xr = reinterpret_cast<const float4*>(x + (size_t)(row0 + r) * DDIM);
#pragma unroll
        for (int i = 0; i < 4; ++i) {
          const int kc4 = q * 4 + i;
          float4 t = xr[kc4];
          xT[(kc4 * 4 + 0) * LDP + r] = t.x;
          xT[(kc4 * 4 + 1) * LDP + r] = t.y;
          xT[(kc4 * 4 + 2) * LDP + r] = t.z;
          xT[(kc4 * 4 + 3) * LDP + r] = t.w;
        }
      }
    }
    __syncthreads();

    float acc[4][4];
#pragma unroll
    for (int i = 0; i < 4; ++i) {
      acc[i][0] = bv.x; acc[i][1] = bv.y; acc[i][2] = bv.z; acc[i][3] = bv.w;
    }
#pragma unroll 8
    for (int k = 0; k < 64; ++k) {
      const float4 xv = *reinterpret_cast<const float4*>(&xT[k * LDP + rg * 4]);
      const float4 wv = *reinterpret_cast<const float4*>(&wT[k * LDP + cg * 4]);
      const float xa[4] = {xv.x, xv.y, xv.z, xv.w};
      const float wa[4] = {wv.x, wv.y, wv.z, wv.w};
#pragma unroll
      for (int i = 0; i < 4; ++i)
#pragma unroll
        for (int j = 0; j < 4; ++j) acc[i][j] += xa[i] * wa[j];
    }
#pragma unroll
    for (int i = 0; i < 4; ++i) {
      const int r = rg * 4 + i;
      if (r < nrows) {
        uint2 o = make_uint2(pack_bf2(acc[i][0], acc[i][1]),
                             pack_bf2(acc[i][2], acc[i][3]));
        reinterpret_cast<uint2*>(y + (size_t)(row0 + r) * 32)[cg] = o;
      }
    }
  }
}

__global__ __launch_bounds__(256) void linear_fused_kernel(
    const float* __restrict__ xu, const float* __restrict__ Wu,
    const float* __restrict__ bu, unsigned int* __restrict__ yu,
    const float* __restrict__ xe, const float* __restrict__ We,
    const float* __restrict__ be, unsigned int* __restrict__ ye) {
  if (blockIdx.x < LGU) {
    linear_tiles(xu, Wu, bu, yu, NUM_USER, (NUM_USER + 63) / 64, blockIdx.x, LGU);
  } else {
    linear_tiles(xe, We, be, ye, NUM_EVENT, (NUM_EVENT + 63) / 64, blockIdx.x - LGU, LGE);
  }
}

// ---------------- Fused gather aggregation ----------------
// Persistent half-wave per node-stream; lane dl = dim pair (uint of 2 bf16).
// Depth-4 load batching: 4 list loads then 4 row loads in flight per step.
// offs is END-position array: segment g spans [offs[g-1], offs[g]).
template <typename IdxT>
__device__ __forceinline__ void gather_range(
    const int* __restrict__ offs, const IdxT* __restrict__ lists,
    const unsigned int* __restrict__ lin_self,
    const unsigned int* __restrict__ lin_other, float* __restrict__ out,
    int n, int obase, int lbase, int stream_id, int nstreams, int dl) {
  for (int node = stream_id; node < n; node += nstreams) {
    const int g = obase + node;
    const int start = (g == 0) ? 0 : offs[g - 1];
    const int end = offs[g];

    const unsigned int sv = lin_self[(size_t)node * 32 + dl];
    float ax = bf_lo(sv), ay = bf_hi(sv);

    int j = start;
    for (; j + 4 <= end; j += 4) {
      const int o0 = (int)lists[j - lbase];
      const int o1 = (int)lists[j + 1 - lbase];
      const int o2 = (int)lists[j + 2 - lbase];
      const int o3 = (int)lists[j + 3 - lbase];
      const unsigned int v0 = lin_other[(size_t)o0 * 32 + dl];
      const unsigned int v1 = lin_other[(size_t)o1 * 32 + dl];
      const unsigned int v2 = lin_other[(size_t)o2 * 32 + dl];
      const unsigned int v3 = lin_other[(size_t)o3 * 32 + dl];
      ax += bf_lo(v0); ay += bf_hi(v0);
      ax += bf_lo(v1); ay += bf_hi(v1);
      ax += bf_lo(v2); ay += bf_hi(v2);
      ax += bf_lo(v3); ay += bf_hi(v3);
    }
    for (; j < end; ++j) {
      const int o0 = (int)lists[j - lbase];
      const unsigned int v0 = lin_other[(size_t)o0 * 32 + dl];
      ax += bf_lo(v0); ay += bf_hi(v0);
    }
    const float inv = 1.0f / (float)(end - start + 1);
    reinterpret_cast<float2*>(out)[(size_t)node * 32 + dl] =
        make_float2(ax * inv, ay * inv);
  }
}

__global__ __launch_bounds__(256) void gather_fused_kernel(
    const int* __restrict__ offs, const unsigned short* __restrict__ lists_u,
    const int* __restrict__ lists_e, const unsigned int* __restrict__ lin_u,
    const unsigned int* __restrict__ lin_e, float* __restrict__ out_u,
    float* __restrict__ out_e) {
  const int lane = threadIdx.x & 63;
  const int dl = lane & 31;
  const int hw = ((threadIdx.x >> 6) << 1) | (lane >> 5);  // half-wave 0..7
  if (blockIdx.x < GGU) {
    const int stream = blockIdx.x * 8 + hw;
    gather_range<unsigned short>(offs, lists_u, lin_u, lin_e, out_u, NUM_USER,
                                 0, 0, stream, GGU * 8, dl);
  } else {
    const int stream = (blockIdx.x - GGU) * 8 + hw;
    gather_range<int>(offs, lists_e, lin_e, lin_u, out_e, NUM_EVENT, NUM_USER,
                      NUM_EDGES, stream, GGE * 8, dl);
  }
}

// ---------------- Launch ----------------

extern "C" void kernel_launch(void* const* d_in, const int* in_sizes, int n_in,
                              void* d_out, int out_size, void* d_ws,
                              size_t ws_size, hipStream_t stream) {
  const float* x_user = (const float*)d_in[0];
  const float* x_event = (const float*)d_in[1];
  const int* src = (const int*)d_in[2];
  const int* dst = (const int*)d_in[3];
  const float* Wu0 = (const float*)d_in[4];
  const float* bu0 = (const float*)d_in[5];
  const float* We0 = (const float*)d_in[6];
  const float* be0 = (const float*)d_in[7];
  const float* Wu1 = (const float*)d_in[8];
  const float* bu1 = (const float*)d_in[9];
  const float* We1 = (const float*)d_in[10];
  const float* be1 = (const float*)d_in[11];

  unsigned int* lin_u = (unsigned int*)d_ws;            // 6.4M u32
  unsigned int* lin_e = lin_u + (size_t)NUM_USER * 32;  // 1.6M u32
  int* offs = (int*)(lin_e + (size_t)NUM_EVENT * 32);   // 250,000
  int* bc = offs + (NUM_USER + NUM_EVENT);              // 294
  int* bbase = bc + NB;                                 // 295
  int* gcur = bbase + NB + 1;                           // 294
  unsigned int* itemsU = (unsigned int*)(gcur + NB);    // 1M
  unsigned int* itemsE = itemsU + NUM_EDGES;            // 1M
  int* lists_e = (int*)(itemsE + NUM_EDGES);            // 1M int
  unsigned short* lists_u = (unsigned short*)(lists_e + NUM_EDGES);  // 1M u16

  float* out_u = (float*)d_out;
  float* out_e = out_u + (size_t)NUM_USER * DDIM;

  // --- CSR build (bucketed counting sort; shared by both layers) ---
  hipMemsetAsync(bc, 0, NB * sizeof(int), stream);
  bucket_count_kernel<<<NCH, 256, 0, stream>>>(src, dst, bc);
  bucket_scan_kernel<<<1, 512, 0, stream>>>(bc, bbase, gcur);
  bucket_scatter_kernel<<<NCH, 256, 0, stream>>>(src, dst, gcur, itemsU, itemsE);
  build_user_kernel<<<NBU, 256, 0, stream>>>(bbase, itemsU, offs, lists_u);
  build_event_kernel<<<NBE, 256, 0, stream>>>(bbase, itemsE, offs, lists_e);

  // ---- Layer 1 ----
  linear_fused_kernel<<<LGU + LGE, 256, 0, stream>>>(
      x_user, Wu0, bu0, lin_u, x_event, We0, be0, lin_e);
  gather_fused_kernel<<<GGU + GGE, 256, 0, stream>>>(
      offs, lists_u, lists_e, lin_u, lin_e, out_u, out_e);

  // ---- Layer 2 ----
  linear_fused_kernel<<<LGU + LGE, 256, 0, stream>>>(
      out_u, Wu1, bu1, lin_u, out_e, We1, be1, lin_e);
  gather_fused_kernel<<<GGU + GGE, 256, 0, stream>>>(
      offs, lists_u, lists_e, lin_u, lin_e, out_u, out_e);
}

// Round 6
// 411.146 us; speedup vs baseline: 3.5277x; 1.0635x over previous
//
#include <hip/hip_runtime.h>

#define NUM_USER 200000
#define NUM_EVENT 50000
#define NUM_EDGES 1000000
#define DDIM 64
#define LDP 68  // LDS leading dim for linear tiles

// Bucketed CSR build: user buckets span 2048 nodes, event buckets span 256.
#define NBU 98                 // 98*2048 = 200704 >= NUM_USER
#define NBE 196                // 196*256 = 50176 >= NUM_EVENT
#define NB (NBU + NBE)         // 294
#define CHUNK 8192
#define NCH ((NUM_EDGES + CHUNK - 1) / CHUNK)  // 123

// Fused-linear grid split (balanced: 3125/1024 ~= 782/256 tiles per block)
#define LGU 1024
#define LGE 256
// Gather: persistent grid, phase-sequential (all waves do users, then events)
#define GGRID 2048

// bf16 pair packing: lin tables stored as uint = (bf16(hi)<<16)|bf16(lo).
__device__ __forceinline__ unsigned int pack_bf2(float lo, float hi) {
  unsigned int ul = __float_as_uint(lo);
  unsigned int uh = __float_as_uint(hi);
  ul = (ul + 0x7FFFu + ((ul >> 16) & 1u)) >> 16;
  uh = (uh + 0x7FFFu + ((uh >> 16) & 1u)) & 0xFFFF0000u;
  return uh | ul;
}
__device__ __forceinline__ float bf_lo(unsigned int v) { return __uint_as_float(v << 16); }
__device__ __forceinline__ float bf_hi(unsigned int v) { return __uint_as_float(v & 0xFFFF0000u); }

// ---------------- CSR build: pass A (bucket histogram) ----------------

__global__ __launch_bounds__(256) void bucket_count_kernel(
    const int* __restrict__ src, const int* __restrict__ dst,
    int* __restrict__ bc) {
  __shared__ int cnt[NB];
  for (int i = threadIdx.x; i < NB; i += 256) cnt[i] = 0;
  __syncthreads();
  const int e0 = blockIdx.x * CHUNK;
  const int e1 = min(e0 + CHUNK, NUM_EDGES);
  for (int i = e0 + threadIdx.x; i < e1; i += 256) {
    atomicAdd(&cnt[dst[i] >> 11], 1);
    atomicAdd(&cnt[NBU + (src[i] >> 8)], 1);
  }
  __syncthreads();
  for (int i = threadIdx.x; i < NB; i += 256)
    if (cnt[i]) atomicAdd(&bc[i], cnt[i]);
}

__global__ __launch_bounds__(512) void bucket_scan_kernel(
    const int* __restrict__ bc, int* __restrict__ bbase, int* __restrict__ gcur) {
  __shared__ int s[512];
  const int tid = threadIdx.x;
  int v = (tid < NB) ? bc[tid] : 0;
  s[tid] = v;
  __syncthreads();
  for (int off = 1; off < 512; off <<= 1) {
    int t = (tid >= off) ? s[tid - off] : 0;
    __syncthreads();
    s[tid] += t;
    __syncthreads();
  }
  if (tid < NB) {
    int excl = s[tid] - v;
    bbase[tid] = excl;
    gcur[tid] = excl - ((tid >= NBU) ? NUM_EDGES : 0);
  }
  if (tid == 0) bbase[NB] = 2 * NUM_EDGES;
}

// Pass A2: scatter packed items into bucket-contiguous runs.
// itemU = (dst&2047)<<16 | src ; itemE = (src&255)<<18 | dst
__global__ __launch_bounds__(256) void bucket_scatter_kernel(
    const int* __restrict__ src, const int* __restrict__ dst,
    int* __restrict__ gcur, unsigned int* __restrict__ itemsU,
    unsigned int* __restrict__ itemsE) {
  __shared__ int cnt[NB];
  __shared__ int cur[NB];
  for (int i = threadIdx.x; i < NB; i += 256) cnt[i] = 0;
  __syncthreads();
  const int e0 = blockIdx.x * CHUNK;
  const int e1 = min(e0 + CHUNK, NUM_EDGES);
  for (int i = e0 + threadIdx.x; i < e1; i += 256) {
    atomicAdd(&cnt[dst[i] >> 11], 1);
    atomicAdd(&cnt[NBU + (src[i] >> 8)], 1);
  }
  __syncthreads();
  for (int i = threadIdx.x; i < NB; i += 256) {
    int c = cnt[i];
    cur[i] = c ? atomicAdd(&gcur[i], c) : 0;
  }
  __syncthreads();
  for (int i = e0 + threadIdx.x; i < e1; i += 256) {
    const int s = src[i];
    const int d = dst[i];
    int r = atomicAdd(&cur[d >> 11], 1);
    itemsU[r] = ((unsigned int)(d & 2047) << 16) | (unsigned int)s;
    int r2 = atomicAdd(&cur[NBU + (s >> 8)], 1);
    itemsE[r2] = ((unsigned int)(s & 255) << 18) | (unsigned int)d;
  }
}

// Pass B (user): one block per bucket.
__global__ __launch_bounds__(256) void build_user_kernel(
    const int* __restrict__ bbase, const unsigned int* __restrict__ itemsU,
    int* __restrict__ offs, unsigned short* __restrict__ lists_u) {
  __shared__ int cnt[2048];
  __shared__ int part[256];
  const int b = blockIdx.x;
  const int istart = bbase[b];
  const int iend = bbase[b + 1];
  const int tid = threadIdx.x;
  for (int i = tid; i < 2048; i += 256) cnt[i] = 0;
  __syncthreads();
  for (int i = istart + tid; i < iend; i += 256)
    atomicAdd(&cnt[itemsU[i] >> 16], 1);
  __syncthreads();
  int v[8];
  int sum = 0;
#pragma unroll
  for (int j = 0; j < 8; ++j) {
    v[j] = cnt[tid * 8 + j];
    sum += v[j];
  }
  part[tid] = sum;
  __syncthreads();
  for (int off = 1; off < 256; off <<= 1) {
    int t = (tid >= off) ? part[tid - off] : 0;
    __syncthreads();
    part[tid] += t;
    __syncthreads();
  }
  int run = (tid == 0) ? 0 : part[tid - 1];
  const int node0 = b * 2048;
#pragma unroll
  for (int j = 0; j < 8; ++j) {
    const int n = node0 + tid * 8 + j;
    if (n < NUM_USER) offs[n] = istart + run + v[j];  // END position
    cnt[tid * 8 + j] = run;                           // exclusive -> cursor
    run += v[j];
  }
  __syncthreads();
  for (int i = istart + tid; i < iend; i += 256) {
    const unsigned int it = itemsU[i];
    int r = atomicAdd(&cnt[it >> 16], 1);
    lists_u[istart + r] = (unsigned short)(it & 0xFFFFu);
  }
}

// Pass B (event): one block per bucket of 256 events.
__global__ __launch_bounds__(256) void build_event_kernel(
    const int* __restrict__ bbase, const unsigned int* __restrict__ itemsE,
    int* __restrict__ offs, int* __restrict__ lists_e) {
  __shared__ int cnt[256];
  __shared__ int s2[256];
  const int b = blockIdx.x;
  const int istart = bbase[NBU + b] - NUM_EDGES;
  const int iend = bbase[NBU + b + 1] - NUM_EDGES;
  const int tid = threadIdx.x;
  cnt[tid] = 0;
  __syncthreads();
  for (int i = istart + tid; i < iend; i += 256)
    atomicAdd(&cnt[itemsE[i] >> 18], 1);
  __syncthreads();
  const int v = cnt[tid];
  s2[tid] = v;
  __syncthreads();
  for (int off = 1; off < 256; off <<= 1) {
    int t = (tid >= off) ? s2[tid - off] : 0;
    __syncthreads();
    s2[tid] += t;
    __syncthreads();
  }
  const int excl = s2[tid] - v;
  const int e0 = b * 256;
  if (e0 + tid < NUM_EVENT)
    offs[NUM_USER + e0 + tid] = NUM_EDGES + istart + excl + v;  // END position
  cnt[tid] = excl;
  __syncthreads();
  for (int i = istart + tid; i < iend; i += 256) {
    const unsigned int it = itemsE[i];
    int r = atomicAdd(&cnt[it >> 18], 1);
    lists_e[istart + r] = (int)(it & 0x3FFFFu);
  }
}

// ---------------- Fused linear: y = x @ W^T + b, fp32 in, bf16-packed out ----------------

__device__ __forceinline__ void linear_tiles(
    const float* __restrict__ x, const float* __restrict__ W,
    const float* __restrict__ b, unsigned int* __restrict__ y, int n,
    int ntiles, int bid, int nblocks) {
  __shared__ float xT[64 * LDP];  // xT[k][r]
  __shared__ float wT[64 * LDP];  // wT[k][c] = W[c][k]
  const int tid = threadIdx.x;
  const int r64 = tid & 63;
  const int q = tid >> 6;

  {  // Stage W^T once per block.
    const int c = r64;
    const float4* wr = reinterpret_cast<const float4*>(W + (size_t)c * DDIM);
#pragma unroll
    for (int i = 0; i < 4; ++i) {
      const int kc4 = q * 4 + i;
      float4 t = wr[kc4];
      wT[(kc4 * 4 + 0) * LDP + c] = t.x;
      wT[(kc4 * 4 + 1) * LDP + c] = t.y;
      wT[(kc4 * 4 + 2) * LDP + c] = t.z;
      wT[(kc4 * 4 + 3) * LDP + c] = t.w;
    }
  }

  const int cg = tid & 15;  // cols cg*4..cg*4+3
  const int rg = tid >> 4;  // rows rg*4..rg*4+3
  const float4 bv = reinterpret_cast<const float4*>(b)[cg];

  for (int tile = bid; tile < ntiles; tile += nblocks) {
    const int row0 = tile * 64;
    const int nrows = min(64, n - row0);
    __syncthreads();  // prior-iter readers done (also publishes W on first iter)
    {
      const int r = r64;
      if (r < nrows) {
        const float4* xr = reinterpret_cast<const float4*>(x + (size_t)(row0 + r) * DDIM);
#pragma unroll
        for (int i = 0; i < 4; ++i) {
          const int kc4 = q * 4 + i;
          float4 t = xr[kc4];
          xT[(kc4 * 4 + 0) * LDP + r] = t.x;
          xT[(kc4 * 4 + 1) * LDP + r] = t.y;
          xT[(kc4 * 4 + 2) * LDP + r] = t.z;
          xT[(kc4 * 4 + 3) * LDP + r] = t.w;
        }
      }
    }
    __syncthreads();

    float acc[4][4];
#pragma unroll
    for (int i = 0; i < 4; ++i) {
      acc[i][0] = bv.x; acc[i][1] = bv.y; acc[i][2] = bv.z; acc[i][3] = bv.w;
    }
#pragma unroll 8
    for (int k = 0; k < 64; ++k) {
      const float4 xv = *reinterpret_cast<const float4*>(&xT[k * LDP + rg * 4]);
      const float4 wv = *reinterpret_cast<const float4*>(&wT[k * LDP + cg * 4]);
      const float xa[4] = {xv.x, xv.y, xv.z, xv.w};
      const float wa[4] = {wv.x, wv.y, wv.z, wv.w};
#pragma unroll
      for (int i = 0; i < 4; ++i)
#pragma unroll
        for (int j = 0; j < 4; ++j) acc[i][j] += xa[i] * wa[j];
    }
#pragma unroll
    for (int i = 0; i < 4; ++i) {
      const int r = rg * 4 + i;
      if (r < nrows) {
        uint2 o = make_uint2(pack_bf2(acc[i][0], acc[i][1]),
                             pack_bf2(acc[i][2], acc[i][3]));
        reinterpret_cast<uint2*>(y + (size_t)(row0 + r) * 32)[cg] = o;
      }
    }
  }
}

__global__ __launch_bounds__(256) void linear_fused_kernel(
    const float* __restrict__ xu, const float* __restrict__ Wu,
    const float* __restrict__ bu, unsigned int* __restrict__ yu,
    const float* __restrict__ xe, const float* __restrict__ We,
    const float* __restrict__ be, unsigned int* __restrict__ ye) {
  if (blockIdx.x < LGU) {
    linear_tiles(xu, Wu, bu, yu, NUM_USER, (NUM_USER + 63) / 64, blockIdx.x, LGU);
  } else {
    linear_tiles(xe, We, be, ye, NUM_EVENT, (NUM_EVENT + 63) / 64, blockIdx.x - LGU, LGE);
  }
}

// ---------------- Fused gather aggregation (phase-sequential, prefetched) ----------------
// Half-wave per node; lane dl = dim pair. Next node's offs/self-row loads are
// issued BEFORE the current node's neighbor loop so their latency hides under
// the gather burst. offs is END-position: segment g spans [offs[g-1], offs[g]).
template <typename IdxT>
__device__ __forceinline__ void gather_phase(
    const int* __restrict__ offs, const IdxT* __restrict__ lists,
    const unsigned int* __restrict__ lin_self,
    const unsigned int* __restrict__ lin_other, float* __restrict__ out,
    int n, int obase, int lbase, int stream_id, int nstreams, int dl) {
  int node = stream_id;
  if (node >= n) return;
  int g = obase + node;
  int start = (g == 0) ? 0 : offs[g - 1];
  int end = offs[g];
  unsigned int sv = lin_self[(size_t)node * 32 + dl];

  while (true) {
    // Prefetch next node's descriptors (issued before the gather chain).
    const int nnode = node + nstreams;
    int nstart = 0, nend = 0;
    unsigned int nsv = 0;
    if (nnode < n) {
      const int ng = obase + nnode;
      nstart = offs[ng - 1];
      nend = offs[ng];
      nsv = lin_self[(size_t)nnode * 32 + dl];
    }

    float ax = bf_lo(sv), ay = bf_hi(sv);
    int j = start;
    for (; j + 4 <= end; j += 4) {
      const int o0 = (int)lists[j - lbase];
      const int o1 = (int)lists[j + 1 - lbase];
      const int o2 = (int)lists[j + 2 - lbase];
      const int o3 = (int)lists[j + 3 - lbase];
      const unsigned int v0 = lin_other[(size_t)o0 * 32 + dl];
      const unsigned int v1 = lin_other[(size_t)o1 * 32 + dl];
      const unsigned int v2 = lin_other[(size_t)o2 * 32 + dl];
      const unsigned int v3 = lin_other[(size_t)o3 * 32 + dl];
      ax += bf_lo(v0); ay += bf_hi(v0);
      ax += bf_lo(v1); ay += bf_hi(v1);
      ax += bf_lo(v2); ay += bf_hi(v2);
      ax += bf_lo(v3); ay += bf_hi(v3);
    }
    for (; j < end; ++j) {
      const int o0 = (int)lists[j - lbase];
      const unsigned int v0 = lin_other[(size_t)o0 * 32 + dl];
      ax += bf_lo(v0); ay += bf_hi(v0);
    }
    const float inv = 1.0f / (float)(end - start + 1);
    reinterpret_cast<float2*>(out)[(size_t)node * 32 + dl] =
        make_float2(ax * inv, ay * inv);

    if (nnode >= n) break;
    node = nnode;
    start = nstart;
    end = nend;
    sv = nsv;
  }
}

__global__ __launch_bounds__(256) void gather_fused_kernel(
    const int* __restrict__ offs, const unsigned short* __restrict__ lists_u,
    const int* __restrict__ lists_e, const unsigned int* __restrict__ lin_u,
    const unsigned int* __restrict__ lin_e, float* __restrict__ out_u,
    float* __restrict__ out_e) {
  const int lane = threadIdx.x & 63;
  const int dl = lane & 31;
  const int hw = ((blockIdx.x * (blockDim.x >> 6) + (threadIdx.x >> 6)) << 1) |
                 (lane >> 5);              // global half-wave id
  const int nstreams = GGRID * 8;          // 16384 streams, both phases
  gather_phase<unsigned short>(offs, lists_u, lin_u, lin_e, out_u, NUM_USER,
                               0, 0, hw, nstreams, dl);
  gather_phase<int>(offs, lists_e, lin_e, lin_u, out_e, NUM_EVENT, NUM_USER,
                    NUM_EDGES, hw, nstreams, dl);
}

// ---------------- Launch ----------------

extern "C" void kernel_launch(void* const* d_in, const int* in_sizes, int n_in,
                              void* d_out, int out_size, void* d_ws,
                              size_t ws_size, hipStream_t stream) {
  const float* x_user = (const float*)d_in[0];
  const float* x_event = (const float*)d_in[1];
  const int* src = (const int*)d_in[2];
  const int* dst = (const int*)d_in[3];
  const float* Wu0 = (const float*)d_in[4];
  const float* bu0 = (const float*)d_in[5];
  const float* We0 = (const float*)d_in[6];
  const float* be0 = (const float*)d_in[7];
  const float* Wu1 = (const float*)d_in[8];
  const float* bu1 = (const float*)d_in[9];
  const float* We1 = (const float*)d_in[10];
  const float* be1 = (const float*)d_in[11];

  unsigned int* lin_u = (unsigned int*)d_ws;            // 6.4M u32
  unsigned int* lin_e = lin_u + (size_t)NUM_USER * 32;  // 1.6M u32
  int* offs = (int*)(lin_e + (size_t)NUM_EVENT * 32);   // 250,000
  int* bc = offs + (NUM_USER + NUM_EVENT);              // 294
  int* bbase = bc + NB;                                 // 295
  int* gcur = bbase + NB + 1;                           // 294
  unsigned int* itemsU = (unsigned int*)(gcur + NB);    // 1M
  unsigned int* itemsE = itemsU + NUM_EDGES;            // 1M
  int* lists_e = (int*)(itemsE + NUM_EDGES);            // 1M int
  unsigned short* lists_u = (unsigned short*)(lists_e + NUM_EDGES);  // 1M u16

  float* out_u = (float*)d_out;
  float* out_e = out_u + (size_t)NUM_USER * DDIM;

  // --- CSR build (bucketed counting sort; shared by both layers) ---
  hipMemsetAsync(bc, 0, NB * sizeof(int), stream);
  bucket_count_kernel<<<NCH, 256, 0, stream>>>(src, dst, bc);
  bucket_scan_kernel<<<1, 512, 0, stream>>>(bc, bbase, gcur);
  bucket_scatter_kernel<<<NCH, 256, 0, stream>>>(src, dst, gcur, itemsU, itemsE);
  build_user_kernel<<<NBU, 256, 0, stream>>>(bbase, itemsU, offs, lists_u);
  build_event_kernel<<<NBE, 256, 0, stream>>>(bbase, itemsE, offs, lists_e);

  // ---- Layer 1 ----
  linear_fused_kernel<<<LGU + LGE, 256, 0, stream>>>(
      x_user, Wu0, bu0, lin_u, x_event, We0, be0, lin_e);
  gather_fused_kernel<<<GGRID, 256, 0, stream>>>(
      offs, lists_u, lists_e, lin_u, lin_e, out_u, out_e);

  // ---- Layer 2 ----
  linear_fused_kernel<<<LGU + LGE, 256, 0, stream>>>(
      out_u, Wu1, bu1, lin_u, out_e, We1, be1, lin_e);
  gather_fused_kernel<<<GGRID, 256, 0, stream>>>(
      offs, lists_u, lists_e, lin_u, lin_e, out_u, out_e);
}